// Round 3
// baseline (1339.613 us; speedup 1.0000x reference)
//
#include <hip/hip_runtime.h>
#include <hip/hip_bf16.h>

#define BT 2048
#define T_SEQ 1024
#define DIM 1024
#define DINNER 2048
#define DSTATE 128
#define HEADDIM 64
#define NHEADS 32
#define CONVCH 2304
#define DINPROJ 4384
#define EPS_F 1e-5f

typedef __bf16 bf16x8 __attribute__((ext_vector_type(8)));
typedef float f32x4 __attribute__((ext_vector_type(4)));

__device__ __forceinline__ float b2f(unsigned short u) {
  union { unsigned int i; float f; } v; v.i = ((unsigned int)u) << 16; return v.f;
}
__device__ __forceinline__ unsigned short f2b(float f) {
  unsigned int x = __float_as_uint(f);
  return (unsigned short)((x + 0x7fffu + ((x >> 16) & 1u)) >> 16);
}

// ---------------- fp32 -> bf16 weight conversion ----------------
__global__ void cvt_k(const float* __restrict__ in, unsigned short* __restrict__ out, int n) {
  int i = (blockIdx.x * 256 + threadIdx.x) * 4;
  if (i < n) {
    float4 v = *(const float4*)(in + i);
    out[i + 0] = f2b(v.x);
    out[i + 1] = f2b(v.y);
    out[i + 2] = f2b(v.z);
    out[i + 3] = f2b(v.w);
  }
}

// ---------------- embed lookup (fp32 table -> fp32 residual + bf16 copy) ----------------
__global__ void embed_k(const int* __restrict__ x, const float* __restrict__ emb,
                        float* __restrict__ h, unsigned short* __restrict__ hb) {
  int t = blockIdx.x;
  int tok = x[t];
  int d = threadIdx.x;
#pragma unroll
  for (int j = 0; j < 4; ++j, d += 256) {
    float v = emb[(size_t)tok * DIM + d];
    h[(size_t)t * DIM + d] = v;
    hb[(size_t)t * DIM + d] = f2b(v);
  }
}

// ---------------- GEMM: C[M,N] = A[M,K] * Bw[N,K]^T (bf16 in, fp32 acc) ----------------
// MODE 0: Cout=bf16 (stride N), cols >= 4352 also dumped fp32 to aux (dt_raw, stride 32)
// MODE 1: aux (fp32, stride N) += acc (residual); aux2 = bf16(aux)
// MODE 2: aux (fp32, stride N) = acc   (final logits, fp32 out)
template <int MODE>
__global__ void gemm_bt(const unsigned short* __restrict__ A,
                        const unsigned short* __restrict__ Bw,
                        int M, int N, int K,
                        unsigned short* __restrict__ Cout,
                        float* __restrict__ aux,
                        unsigned short* __restrict__ aux2) {
  __shared__ __align__(16) unsigned short As[128 * 32];
  __shared__ __align__(16) unsigned short Bs[128 * 32];
  const int tid = threadIdx.x;
  const int lane = tid & 63;
  const int wave = tid >> 6;
  const int m0 = blockIdx.y * 128;
  const int n0 = blockIdx.x * 128;
  const int wm = (wave >> 1) * 64;
  const int wn = (wave & 1) * 64;
  const int quad = lane >> 4;
  const int r = lane & 15;

  f32x4 acc[4][4];
#pragma unroll
  for (int i = 0; i < 4; ++i)
#pragma unroll
    for (int j = 0; j < 4; ++j) acc[i][j] = f32x4{0.f, 0.f, 0.f, 0.f};

  const int idx0 = tid, idx1 = tid + 256;
  const int ra0 = idx0 >> 2, ca0 = (idx0 & 3) * 8;
  const int ra1 = idx1 >> 2, ca1 = (idx1 & 3) * 8;
  int rb0 = n0 + ra0; if (rb0 >= N) rb0 = N - 1;
  int rb1 = n0 + ra1; if (rb1 >= N) rb1 = N - 1;

  for (int k0 = 0; k0 < K; k0 += 32) {
    uint4 a0 = *(const uint4*)(A + (size_t)(m0 + ra0) * K + k0 + ca0);
    uint4 a1 = *(const uint4*)(A + (size_t)(m0 + ra1) * K + k0 + ca1);
    uint4 b0 = *(const uint4*)(Bw + (size_t)rb0 * K + k0 + ca0);
    uint4 b1 = *(const uint4*)(Bw + (size_t)rb1 * K + k0 + ca1);
    __syncthreads();
    *(uint4*)(As + idx0 * 8) = a0;
    *(uint4*)(As + idx1 * 8) = a1;
    *(uint4*)(Bs + idx0 * 8) = b0;
    *(uint4*)(Bs + idx1 * 8) = b1;
    __syncthreads();
    const bf16x8* ap = (const bf16x8*)As;
    const bf16x8* bp = (const bf16x8*)Bs;
    bf16x8 af[4], bfr[4];
#pragma unroll
    for (int mt = 0; mt < 4; ++mt) af[mt] = ap[(wm + mt * 16 + r) * 4 + quad];
#pragma unroll
    for (int nt = 0; nt < 4; ++nt) bfr[nt] = bp[(wn + nt * 16 + r) * 4 + quad];
#pragma unroll
    for (int mt = 0; mt < 4; ++mt)
#pragma unroll
      for (int nt = 0; nt < 4; ++nt)
        acc[mt][nt] = __builtin_amdgcn_mfma_f32_16x16x32_bf16(af[mt], bfr[nt], acc[mt][nt], 0, 0, 0);
  }

#pragma unroll
  for (int mt = 0; mt < 4; ++mt) {
#pragma unroll
    for (int nt = 0; nt < 4; ++nt) {
#pragma unroll
      for (int i = 0; i < 4; ++i) {
        int gm = m0 + wm + mt * 16 + quad * 4 + i;
        int gn = n0 + wn + nt * 16 + r;
        if (gn < N) {
          float v = acc[mt][nt][i];
          if (MODE == 0) {
            Cout[(size_t)gm * N + gn] = f2b(v);
            if (gn >= DINNER + CONVCH)
              aux[(size_t)gm * NHEADS + (gn - (DINNER + CONVCH))] = v;
          } else if (MODE == 1) {
            size_t o = (size_t)gm * N + gn;
            float hnv = aux[o] + v;
            aux[o] = hnv;
            aux2[o] = f2b(hnv);
          } else {
            aux[(size_t)gm * N + gn] = v;
          }
        }
      }
    }
  }
}

// ---------------- causal conv (K=4) + silu; B/C channels also dumped fp32 ----------------
__global__ void conv_k(const unsigned short* __restrict__ zx,
                       const float* __restrict__ cw,
                       const float* __restrict__ cb,
                       unsigned short* __restrict__ xbc,
                       float* __restrict__ bcf) {
  int t = blockIdx.x;
  int tt = t & (T_SEQ - 1);
  for (int c = threadIdx.x; c < CONVCH; c += 256) {
    float acc = cb[c];
#pragma unroll
    for (int k = 0; k < 4; ++k) {
      int tp = tt - 3 + k;
      if (tp >= 0)
        acc += b2f(zx[(size_t)(t - 3 + k) * DINPROJ + DINNER + c]) * cw[c * 4 + k];
    }
    float s = acc / (1.f + expf(-acc));
    xbc[(size_t)t * CONVCH + c] = f2b(s);
    if (c >= DINNER) bcf[(size_t)t * 256 + (c - DINNER)] = s;
  }
}

// ---------------- dt = softplus(dt_raw + bias); dA = exp(-dt * exp(A_log)) ----------------
__global__ void dt_k(const float* __restrict__ dtraw, const float* __restrict__ dtb,
                     const float* __restrict__ alog,
                     float* __restrict__ dtf, float* __restrict__ dAf) {
  int i = blockIdx.x * 256 + threadIdx.x;
  int h = i & (NHEADS - 1);
  float xx = dtraw[i] + dtb[h];
  float sp = (xx > 20.f) ? xx : log1pf(expf(xx));
  dtf[i] = sp;
  dAf[i] = expf(-sp * expf(alog[h]));
}

// ---------------- sequential selective scan, 1 wave per (b,h,p-octant) ------
// Depth-8 register software pipeline: while computing slot k, up to 7 slots of
// global loads are in flight -> hides ~900cyc L3/HBM latency at 2 waves/CU.
#define SCAN_D 8
__global__ __launch_bounds__(64, 1) void scan_k(
    const unsigned short* __restrict__ xbc,
    const float* __restrict__ bcf,
    const unsigned short* __restrict__ zx,
    const float* __restrict__ dtf, const float* __restrict__ dAf,
    const float* __restrict__ Dw,
    unsigned short* __restrict__ yg) {
  const int bi = blockIdx.x;           // 512 = 2b * 32h * 8pblk
  const int b = bi >> 8;
  const int h = (bi >> 3) & 31;
  const int pblk = bi & 7;
  const int tid = threadIdx.x;         // 64
  const int pl = tid & 7;
  const int p = pblk * 8 + pl;
  const int g = tid >> 3;              // 0..7 -> n = g*16 .. g*16+15
  const size_t tok0 = (size_t)b * T_SEQ;

  float s[16];
#pragma unroll
  for (int j = 0; j < 16; ++j) s[j] = 0.f;
  const float Dh = Dw[h];

  float Bv[SCAN_D][16], Cv[SCAN_D][16];
  unsigned short xv[SCAN_D], zv[SCAN_D];
  float dtv[SCAN_D], dav[SCAN_D];

#define SCAN_LOAD(slot, t)                                                     \
  {                                                                            \
    size_t tk = tok0 + (t);                                                    \
    const float4* bp4 = (const float4*)(bcf + tk * 256 + g * 16);              \
    const float4* cp4 = (const float4*)(bcf + tk * 256 + 128 + g * 16);        \
    _Pragma("unroll") for (int q = 0; q < 4; ++q) {                            \
      float4 bq = bp4[q]; float4 cq = cp4[q];                                  \
      Bv[slot][q * 4 + 0] = bq.x; Bv[slot][q * 4 + 1] = bq.y;                  \
      Bv[slot][q * 4 + 2] = bq.z; Bv[slot][q * 4 + 3] = bq.w;                  \
      Cv[slot][q * 4 + 0] = cq.x; Cv[slot][q * 4 + 1] = cq.y;                  \
      Cv[slot][q * 4 + 2] = cq.z; Cv[slot][q * 4 + 3] = cq.w;                  \
    }                                                                          \
    xv[slot] = xbc[tk * CONVCH + h * HEADDIM + p];                             \
    zv[slot] = zx[tk * DINPROJ + h * HEADDIM + p];                             \
    dtv[slot] = dtf[tk * NHEADS + h];                                          \
    dav[slot] = dAf[tk * NHEADS + h];                                          \
  }

#define SCAN_COMP(slot, t)                                                     \
  {                                                                            \
    float xvf = b2f(xv[slot]);                                                 \
    float coef = dtv[slot] * xvf;                                              \
    float da = dav[slot];                                                      \
    float a0 = 0.f, a1 = 0.f, a2 = 0.f, a3 = 0.f;                              \
    _Pragma("unroll") for (int j = 0; j < 4; ++j) {                            \
      s[j +  0] = fmaf(da, s[j +  0], coef * Bv[slot][j +  0]);                \
      s[j +  4] = fmaf(da, s[j +  4], coef * Bv[slot][j +  4]);                \
      s[j +  8] = fmaf(da, s[j +  8], coef * Bv[slot][j +  8]);                \
      s[j + 12] = fmaf(da, s[j + 12], coef * Bv[slot][j + 12]);                \
      a0 = fmaf(s[j +  0], Cv[slot][j +  0], a0);                              \
      a1 = fmaf(s[j +  4], Cv[slot][j +  4], a1);                              \
      a2 = fmaf(s[j +  8], Cv[slot][j +  8], a2);                              \
      a3 = fmaf(s[j + 12], Cv[slot][j + 12], a3);                              \
    }                                                                          \
    float acc = (a0 + a1) + (a2 + a3);                                         \
    acc += __shfl_xor(acc, 8, 64);                                             \
    acc += __shfl_xor(acc, 16, 64);                                            \
    acc += __shfl_xor(acc, 32, 64);                                            \
    if (g == 0) {                                                              \
      float zf = b2f(zv[slot]);                                                \
      float gate = zf / (1.f + expf(-zf));                                     \
      float yv = (acc + Dh * xvf) * gate;                                      \
      yg[(tok0 + (t)) * DINNER + h * HEADDIM + p] = f2b(yv);                   \
    }                                                                          \
  }

#pragma unroll
  for (int k = 0; k < SCAN_D; ++k) SCAN_LOAD(k, k);

  int t = 0;
  for (; t < T_SEQ - SCAN_D; t += SCAN_D) {
#pragma unroll
    for (int k = 0; k < SCAN_D; ++k) {
      SCAN_COMP(k, t + k);
      SCAN_LOAD(k, t + SCAN_D + k);
    }
  }
#pragma unroll
  for (int k = 0; k < SCAN_D; ++k) SCAN_COMP(k, t + k);

#undef SCAN_LOAD
#undef SCAN_COMP
}

// ---------------- RMSNorm over 2048 (bf16 in/out, fp32 weight) ----------------
__global__ void rms2048_k(const unsigned short* __restrict__ in,
                          const float* __restrict__ w,
                          unsigned short* __restrict__ out) {
  int t = blockIdx.x;
  int base = threadIdx.x * 8;
  union { uint4 q; unsigned short u[8]; } vv;
  vv.q = *(const uint4*)(in + (size_t)t * DINNER + base);
  float f[8];
  float ss = 0.f;
#pragma unroll
  for (int j = 0; j < 8; ++j) { f[j] = b2f(vv.u[j]); ss += f[j] * f[j]; }
#pragma unroll
  for (int o = 32; o > 0; o >>= 1) ss += __shfl_xor(ss, o, 64);
  __shared__ float red[4];
  if ((threadIdx.x & 63) == 0) red[threadIdx.x >> 6] = ss;
  __syncthreads();
  ss = red[0] + red[1] + red[2] + red[3];
  float scale = rsqrtf(ss * (1.f / DINNER) + EPS_F);
#pragma unroll
  for (int j = 0; j < 8; ++j)
    out[(size_t)t * DINNER + base + j] = f2b(f[j] * scale * w[base + j]);
}

// ---------------- final RMSNorm over 1024 (fp32 in, fp32 weight, bf16 out) ----------------
__global__ void rmsfinal_k(const float* __restrict__ hf,
                           const float* __restrict__ w,
                           unsigned short* __restrict__ out) {
  int t = blockIdx.x;
  int base = threadIdx.x * 4;
  float4 v = *(const float4*)(hf + (size_t)t * DIM + base);
  float ss = v.x * v.x + v.y * v.y + v.z * v.z + v.w * v.w;
#pragma unroll
  for (int o = 32; o > 0; o >>= 1) ss += __shfl_xor(ss, o, 64);
  __shared__ float red[4];
  if ((threadIdx.x & 63) == 0) red[threadIdx.x >> 6] = ss;
  __syncthreads();
  ss = red[0] + red[1] + red[2] + red[3];
  float scale = rsqrtf(ss * (1.f / DIM) + EPS_F);
  out[(size_t)t * DIM + base + 0] = f2b(v.x * scale * w[base + 0]);
  out[(size_t)t * DIM + base + 1] = f2b(v.y * scale * w[base + 1]);
  out[(size_t)t * DIM + base + 2] = f2b(v.z * scale * w[base + 2]);
  out[(size_t)t * DIM + base + 3] = f2b(v.w * scale * w[base + 3]);
}

extern "C" void kernel_launch(void* const* d_in, const int* in_sizes, int n_in,
                              void* d_out, int out_size, void* d_ws, size_t ws_size,
                              hipStream_t stream) {
  const int*   x    = (const int*)d_in[0];
  const float* emb  = (const float*)d_in[1];
  const float* Wp   = (const float*)d_in[2];
  const float* cw   = (const float*)d_in[3];
  const float* cb   = (const float*)d_in[4];
  const float* dtb  = (const float*)d_in[5];
  const float* alog = (const float*)d_in[6];
  const float* Dw   = (const float*)d_in[7];
  const float* gw   = (const float*)d_in[8];
  const float* Wo   = (const float*)d_in[9];
  const float* fnw  = (const float*)d_in[10];

  char* w = (char*)d_ws;
  auto alloc = [&](size_t bytes) {
    char* p = w; w += (bytes + 255) & ~(size_t)255; return p;
  };
  float* h_f32          = (float*)alloc((size_t)BT * DIM * 4);
  unsigned short* hb    = (unsigned short*)alloc((size_t)BT * DIM * 2);
  unsigned short* zx    = (unsigned short*)alloc((size_t)BT * DINPROJ * 2);
  float* dtraw          = (float*)alloc((size_t)BT * NHEADS * 4);
  float* dtf            = (float*)alloc((size_t)BT * NHEADS * 4);
  float* dAf            = (float*)alloc((size_t)BT * NHEADS * 4);
  unsigned short* xbc   = (unsigned short*)alloc((size_t)BT * CONVCH * 2);
  float* bcf            = (float*)alloc((size_t)BT * 256 * 4);
  unsigned short* yg    = (unsigned short*)alloc((size_t)BT * DINNER * 2);
  unsigned short* yn    = (unsigned short*)alloc((size_t)BT * DINNER * 2);
  unsigned short* hn    = (unsigned short*)alloc((size_t)BT * DIM * 2);
  unsigned short* Wp_b  = (unsigned short*)alloc((size_t)2 * DINPROJ * DIM * 2);
  unsigned short* Wo_b  = (unsigned short*)alloc((size_t)2 * DIM * DINNER * 2);
  unsigned short* emb_b = (unsigned short*)alloc((size_t)256 * DIM * 2);

  // fp32 -> bf16 weight conversions
  {
    int nWp = 2 * DINPROJ * DIM;
    int nWo = 2 * DIM * DINNER;
    int nEm = 256 * DIM;
    cvt_k<<<(nWp / 4 + 255) / 256, 256, 0, stream>>>(Wp, Wp_b, nWp);
    cvt_k<<<(nWo / 4 + 255) / 256, 256, 0, stream>>>(Wo, Wo_b, nWo);
    cvt_k<<<(nEm / 4 + 255) / 256, 256, 0, stream>>>(emb, emb_b, nEm);
  }

  embed_k<<<BT, 256, 0, stream>>>(x, emb, h_f32, hb);

  for (int l = 0; l < 2; ++l) {
    const unsigned short* Wpl = Wp_b + (size_t)l * DINPROJ * DIM;
    const unsigned short* Wol = Wo_b + (size_t)l * DIM * DINNER;
    const float* cwl   = cw + (size_t)l * CONVCH * 4;
    const float* cbl   = cb + (size_t)l * CONVCH;
    const float* dtbl  = dtb + l * NHEADS;
    const float* alogl = alog + l * NHEADS;
    const float* Dwl   = Dw + l * NHEADS;
    const float* gwl   = gw + (size_t)l * DINNER;

    gemm_bt<0><<<dim3(35, 16), 256, 0, stream>>>(hb, Wpl, BT, DINPROJ, DIM, zx, dtraw, nullptr);
    conv_k<<<BT, 256, 0, stream>>>(zx, cwl, cbl, xbc, bcf);
    dt_k<<<BT * NHEADS / 256, 256, 0, stream>>>(dtraw, dtbl, alogl, dtf, dAf);
    scan_k<<<512, 64, 0, stream>>>(xbc, bcf, zx, dtf, dAf, Dwl, yg);
    rms2048_k<<<BT, 256, 0, stream>>>(yg, gwl, yn);
    gemm_bt<1><<<dim3(8, 16), 256, 0, stream>>>(yn, Wol, BT, DIM, DINNER, nullptr, h_f32, hb);
  }

  rmsfinal_k<<<BT, 256, 0, stream>>>(h_f32, fnw, hn);
  gemm_bt<2><<<dim3(2, 16), 256, 0, stream>>>(hn, emb_b, BT, 256, DIM,
                                              nullptr, (float*)d_out, nullptr);
}

// Round 4
// 1077.526 us; speedup vs baseline: 1.2432x; 1.2432x over previous
//
#include <hip/hip_runtime.h>
#include <hip/hip_bf16.h>

#define BT 2048
#define T_SEQ 1024
#define DIM 1024
#define DINNER 2048
#define DSTATE 128
#define HEADDIM 64
#define NHEADS 32
#define CONVCH 2304
#define DINPROJ 4384
#define EPS_F 1e-5f
#define CHUNK 16

typedef __bf16 bf16x8 __attribute__((ext_vector_type(8)));
typedef float f32x4 __attribute__((ext_vector_type(4)));

__device__ __forceinline__ float b2f(unsigned short u) {
  union { unsigned int i; float f; } v; v.i = ((unsigned int)u) << 16; return v.f;
}
__device__ __forceinline__ unsigned short f2b(float f) {
  unsigned int x = __float_as_uint(f);
  return (unsigned short)((x + 0x7fffu + ((x >> 16) & 1u)) >> 16);
}

// async global->LDS DMA: each lane loads 16B from its gptr; lands at
// wave-uniform ldsbase + lane*16 (m97/m104 semantics). Zero VGPR cost.
__device__ __forceinline__ void gload_lds16(const void* g, void* l) {
  __builtin_amdgcn_global_load_lds(
      (const __attribute__((address_space(1))) unsigned int*)g,
      (__attribute__((address_space(3))) unsigned int*)l, 16, 0, 0);
}

// ---------------- fp32 -> bf16 weight conversion ----------------
__global__ void cvt_k(const float* __restrict__ in, unsigned short* __restrict__ out, int n) {
  int i = (blockIdx.x * 256 + threadIdx.x) * 4;
  if (i < n) {
    float4 v = *(const float4*)(in + i);
    out[i + 0] = f2b(v.x);
    out[i + 1] = f2b(v.y);
    out[i + 2] = f2b(v.z);
    out[i + 3] = f2b(v.w);
  }
}

// ---------------- embed lookup (fp32 table -> fp32 residual + bf16 copy) ----------------
__global__ void embed_k(const int* __restrict__ x, const float* __restrict__ emb,
                        float* __restrict__ h, unsigned short* __restrict__ hb) {
  int t = blockIdx.x;
  int tok = x[t];
  int d = threadIdx.x;
#pragma unroll
  for (int j = 0; j < 4; ++j, d += 256) {
    float v = emb[(size_t)tok * DIM + d];
    h[(size_t)t * DIM + d] = v;
    hb[(size_t)t * DIM + d] = f2b(v);
  }
}

// ---------------- GEMM: C[M,N] = A[M,K] * Bw[N,K]^T (bf16 in, fp32 acc) ----------------
// m97 structure: global_load_lds staging, 2-barrier K-loop.
// MODE 0: Cout=bf16 (stride N), cols >= 4352 also dumped fp32 to aux (dt_raw, stride 32)
// MODE 1: aux (fp32, stride N) += acc (residual); aux2 = bf16(aux)
// MODE 2: aux (fp32, stride N) = acc   (final logits, fp32 out)
template <int MODE>
__global__ void gemm_bt(const unsigned short* __restrict__ A,
                        const unsigned short* __restrict__ Bw,
                        int M, int N, int K,
                        unsigned short* __restrict__ Cout,
                        float* __restrict__ aux,
                        unsigned short* __restrict__ aux2) {
  __shared__ __align__(16) unsigned short As[128 * 32];
  __shared__ __align__(16) unsigned short Bs[128 * 32];
  const int tid = threadIdx.x;
  const int lane = tid & 63;
  const int wave = tid >> 6;
  const int m0 = blockIdx.y * 128;
  const int n0 = blockIdx.x * 128;
  const int wm = (wave >> 1) * 64;
  const int wn = (wave & 1) * 64;
  const int quad = lane >> 4;
  const int r = lane & 15;

  f32x4 acc[4][4];
#pragma unroll
  for (int i = 0; i < 4; ++i)
#pragma unroll
    for (int j = 0; j < 4; ++j) acc[i][j] = f32x4{0.f, 0.f, 0.f, 0.f};

  const int idx0 = tid, idx1 = tid + 256;
  const int ra0 = idx0 >> 2, ca0 = (idx0 & 3) * 8;
  const int ra1 = idx1 >> 2, ca1 = (idx1 & 3) * 8;
  int rb0 = n0 + ra0; if (rb0 >= N) rb0 = N - 1;
  int rb1 = n0 + ra1; if (rb1 >= N) rb1 = N - 1;

  // LDS dest bases (wave-uniform): idx*8 = (chunk region) + lane*8 shorts
  unsigned short* asD0 = As + wave * 512;
  unsigned short* asD1 = As + 2048 + wave * 512;
  unsigned short* bsD0 = Bs + wave * 512;
  unsigned short* bsD1 = Bs + 2048 + wave * 512;
  const unsigned short* aG0 = A + (size_t)(m0 + ra0) * K + ca0;
  const unsigned short* aG1 = A + (size_t)(m0 + ra1) * K + ca1;
  const unsigned short* bG0 = Bw + (size_t)rb0 * K + ca0;
  const unsigned short* bG1 = Bw + (size_t)rb1 * K + ca1;

  for (int k0 = 0; k0 < K; k0 += 32) {
    __syncthreads();
    gload_lds16(aG0 + k0, asD0);
    gload_lds16(aG1 + k0, asD1);
    gload_lds16(bG0 + k0, bsD0);
    gload_lds16(bG1 + k0, bsD1);
    __syncthreads();  // compiler drains vmcnt(0) before s_barrier -> staging visible
    const bf16x8* ap = (const bf16x8*)As;
    const bf16x8* bp = (const bf16x8*)Bs;
    bf16x8 af[4], bfr[4];
#pragma unroll
    for (int mt = 0; mt < 4; ++mt) af[mt] = ap[(wm + mt * 16 + r) * 4 + quad];
#pragma unroll
    for (int nt = 0; nt < 4; ++nt) bfr[nt] = bp[(wn + nt * 16 + r) * 4 + quad];
#pragma unroll
    for (int mt = 0; mt < 4; ++mt)
#pragma unroll
      for (int nt = 0; nt < 4; ++nt)
        acc[mt][nt] = __builtin_amdgcn_mfma_f32_16x16x32_bf16(af[mt], bfr[nt], acc[mt][nt], 0, 0, 0);
  }

#pragma unroll
  for (int mt = 0; mt < 4; ++mt) {
#pragma unroll
    for (int nt = 0; nt < 4; ++nt) {
#pragma unroll
      for (int i = 0; i < 4; ++i) {
        int gm = m0 + wm + mt * 16 + quad * 4 + i;
        int gn = n0 + wn + nt * 16 + r;
        if (gn < N) {
          float v = acc[mt][nt][i];
          if (MODE == 0) {
            Cout[(size_t)gm * N + gn] = f2b(v);
            if (gn >= DINNER + CONVCH)
              aux[(size_t)gm * NHEADS + (gn - (DINNER + CONVCH))] = v;
          } else if (MODE == 1) {
            size_t o = (size_t)gm * N + gn;
            float hnv = aux[o] + v;
            aux[o] = hnv;
            aux2[o] = f2b(hnv);
          } else {
            aux[(size_t)gm * N + gn] = v;
          }
        }
      }
    }
  }
}

// ---------------- causal conv (K=4) + silu; B/C channels also dumped fp32 ----------------
__global__ void conv_k(const unsigned short* __restrict__ zx,
                       const float* __restrict__ cw,
                       const float* __restrict__ cb,
                       unsigned short* __restrict__ xbc,
                       float* __restrict__ bcf) {
  int t = blockIdx.x;
  int tt = t & (T_SEQ - 1);
  for (int c = threadIdx.x; c < CONVCH; c += 256) {
    float acc = cb[c];
#pragma unroll
    for (int k = 0; k < 4; ++k) {
      int tp = tt - 3 + k;
      if (tp >= 0)
        acc += b2f(zx[(size_t)(t - 3 + k) * DINPROJ + DINNER + c]) * cw[c * 4 + k];
    }
    float s = acc / (1.f + expf(-acc));
    xbc[(size_t)t * CONVCH + c] = f2b(s);
    if (c >= DINNER) bcf[(size_t)t * 256 + (c - DINNER)] = s;
  }
}

// ---------------- dt = softplus(dt_raw + bias); dA = exp(-dt * exp(A_log)) ----------------
__global__ void dt_k(const float* __restrict__ dtraw, const float* __restrict__ dtb,
                     const float* __restrict__ alog,
                     float* __restrict__ dtf, float* __restrict__ dAf) {
  int i = blockIdx.x * 256 + threadIdx.x;
  int h = i & (NHEADS - 1);
  float xx = dtraw[i] + dtb[h];
  float sp = (xx > 20.f) ? xx : log1pf(expf(xx));
  dtf[i] = sp;
  dAf[i] = expf(-sp * expf(alog[h]));
}

// ---------------- sequential selective scan ------------------------------------------
// 1 wave per (b,h,p-octant). B/C staged global->LDS via async DMA (zero VGPR),
// double-buffered 16-token chunks, no barriers (wave-private LDS use).
// x/z prefetched in ping-pong regs; dt/dA loaded once per 64 tokens, shfl-broadcast.
__global__ __launch_bounds__(64, 1) void scan_k(
    const unsigned short* __restrict__ xbc,
    const float* __restrict__ bcf,
    const unsigned short* __restrict__ zx,
    const float* __restrict__ dtf, const float* __restrict__ dAf,
    const float* __restrict__ Dw,
    unsigned short* __restrict__ yg) {
  const int bi = blockIdx.x;           // 512 = 2b * 32h * 8pblk
  const int b = bi >> 8;
  const int h = (bi >> 3) & 31;
  const int pblk = bi & 7;
  const int lane = threadIdx.x;        // 64
  const int pl = lane & 7;
  const int p = pblk * 8 + pl;
  const int g = lane >> 3;             // 0..7 -> n = g*16 .. g*16+15
  const size_t tok0 = (size_t)b * T_SEQ;
  const int cidx = h * HEADDIM + p;

  __shared__ __align__(16) float lbc[2][CHUNK][256];

  float s[16];
#pragma unroll
  for (int j = 0; j < 16; ++j) s[j] = 0.f;
  const float Dh = Dw[h];

  unsigned short xr[2][CHUNK], zr[2][CHUNK];
  float dt_cur = dtf[tok0 + lane];
  float da_cur = dAf[tok0 + lane];
  float dt_nxt = 0.f, da_nxt = 0.f;

  // stage chunk 0 -> buf0 + X[0]
#pragma unroll
  for (int k = 0; k < CHUNK; ++k)
    gload_lds16(bcf + (tok0 + k) * 256 + lane * 4, &lbc[0][k][0]);
#pragma unroll
  for (int k = 0; k < CHUNK; ++k) {
    xr[0][k] = xbc[(tok0 + k) * CONVCH + cidx];
    zr[0][k] = zx[(tok0 + k) * DINPROJ + cidx];
  }

  for (int sc = 0; sc < T_SEQ / 64; ++sc) {
#pragma unroll
    for (int c4 = 0; c4 < 4; ++c4) {
      const int t0 = sc * 64 + c4 * 16;
      const int cur = c4 & 1, nxt = cur ^ 1;
      // wait: current chunk's LDS staging + X-reg loads landed
      __builtin_amdgcn_s_waitcnt(0x0F70);  // vmcnt(0) only
      __builtin_amdgcn_sched_barrier(0);
      // issue staging for next chunk (clamped at sequence end)
#pragma unroll
      for (int k = 0; k < CHUNK; ++k) {
        int tn = t0 + CHUNK + k; if (tn > T_SEQ - 1) tn = T_SEQ - 1;
        gload_lds16(bcf + (tok0 + tn) * 256 + lane * 4, &lbc[nxt][k][0]);
      }
#pragma unroll
      for (int k = 0; k < CHUNK; ++k) {
        int tn = t0 + CHUNK + k; if (tn > T_SEQ - 1) tn = T_SEQ - 1;
        xr[nxt][k] = xbc[(tok0 + tn) * CONVCH + cidx];
        zr[nxt][k] = zx[(tok0 + tn) * DINPROJ + cidx];
      }
      if (c4 == 0) {
        int nsc = (sc + 1 < T_SEQ / 64) ? sc + 1 : sc;
        dt_nxt = dtf[tok0 + nsc * 64 + lane];
        da_nxt = dAf[tok0 + nsc * 64 + lane];
      }
      // compute current chunk
#pragma unroll
      for (int k = 0; k < CHUNK; ++k) {
        const float dta = __shfl(dt_cur, c4 * 16 + k, 64);
        const float daa = __shfl(da_cur, c4 * 16 + k, 64);
        float Bvv[16], Cvv[16];
#pragma unroll
        for (int q = 0; q < 4; ++q) {
          // XOR-rotate read order by g: 4-way bank conflict -> free 2-way.
          // Lane's slot q holds n = g*16 + ((q+g)&3)*4 + j -- fixed mapping, so
          // s[], B, C stay consistent across iterations; dot order is irrelevant.
          const int qq4 = ((q + g) & 3) * 4;
          float4 bq = *(const float4*)&lbc[cur][k][g * 16 + qq4];
          float4 cq = *(const float4*)&lbc[cur][k][128 + g * 16 + qq4];
          Bvv[q * 4 + 0] = bq.x; Bvv[q * 4 + 1] = bq.y;
          Bvv[q * 4 + 2] = bq.z; Bvv[q * 4 + 3] = bq.w;
          Cvv[q * 4 + 0] = cq.x; Cvv[q * 4 + 1] = cq.y;
          Cvv[q * 4 + 2] = cq.z; Cvv[q * 4 + 3] = cq.w;
        }
        const float xvf = b2f(xr[cur][k]);
        const float coef = dta * xvf;
        float a0 = 0.f, a1 = 0.f, a2 = 0.f, a3 = 0.f;
#pragma unroll
        for (int j = 0; j < 4; ++j) {
          s[j +  0] = fmaf(daa, s[j +  0], coef * Bvv[j +  0]);
          s[j +  4] = fmaf(daa, s[j +  4], coef * Bvv[j +  4]);
          s[j +  8] = fmaf(daa, s[j +  8], coef * Bvv[j +  8]);
          s[j + 12] = fmaf(daa, s[j + 12], coef * Bvv[j + 12]);
          a0 = fmaf(s[j +  0], Cvv[j +  0], a0);
          a1 = fmaf(s[j +  4], Cvv[j +  4], a1);
          a2 = fmaf(s[j +  8], Cvv[j +  8], a2);
          a3 = fmaf(s[j + 12], Cvv[j + 12], a3);
        }
        float accv = (a0 + a1) + (a2 + a3);
        accv += __shfl_xor(accv, 8, 64);
        accv += __shfl_xor(accv, 16, 64);
        accv += __shfl_xor(accv, 32, 64);
        if (g == 0) {
          float zf = b2f(zr[cur][k]);
          float gate = zf / (1.f + expf(-zf));
          float yv = (accv + Dh * xvf) * gate;
          yg[(tok0 + t0 + k) * DINNER + cidx] = f2b(yv);
        }
      }
    }
    dt_cur = dt_nxt; da_cur = da_nxt;
  }
}

// ---------------- RMSNorm over 2048 (bf16 in/out, fp32 weight) ----------------
__global__ void rms2048_k(const unsigned short* __restrict__ in,
                          const float* __restrict__ w,
                          unsigned short* __restrict__ out) {
  int t = blockIdx.x;
  int base = threadIdx.x * 8;
  union { uint4 q; unsigned short u[8]; } vv;
  vv.q = *(const uint4*)(in + (size_t)t * DINNER + base);
  float f[8];
  float ss = 0.f;
#pragma unroll
  for (int j = 0; j < 8; ++j) { f[j] = b2f(vv.u[j]); ss += f[j] * f[j]; }
#pragma unroll
  for (int o = 32; o > 0; o >>= 1) ss += __shfl_xor(ss, o, 64);
  __shared__ float red[4];
  if ((threadIdx.x & 63) == 0) red[threadIdx.x >> 6] = ss;
  __syncthreads();
  ss = red[0] + red[1] + red[2] + red[3];
  float scale = rsqrtf(ss * (1.f / DINNER) + EPS_F);
#pragma unroll
  for (int j = 0; j < 8; ++j)
    out[(size_t)t * DINNER + base + j] = f2b(f[j] * scale * w[base + j]);
}

// ---------------- final RMSNorm over 1024 (fp32 in, fp32 weight, bf16 out) ----------------
__global__ void rmsfinal_k(const float* __restrict__ hf,
                           const float* __restrict__ w,
                           unsigned short* __restrict__ out) {
  int t = blockIdx.x;
  int base = threadIdx.x * 4;
  float4 v = *(const float4*)(hf + (size_t)t * DIM + base);
  float ss = v.x * v.x + v.y * v.y + v.z * v.z + v.w * v.w;
#pragma unroll
  for (int o = 32; o > 0; o >>= 1) ss += __shfl_xor(ss, o, 64);
  __shared__ float red[4];
  if ((threadIdx.x & 63) == 0) red[threadIdx.x >> 6] = ss;
  __syncthreads();
  ss = red[0] + red[1] + red[2] + red[3];
  float scale = rsqrtf(ss * (1.f / DIM) + EPS_F);
  out[(size_t)t * DIM + base + 0] = f2b(v.x * scale * w[base + 0]);
  out[(size_t)t * DIM + base + 1] = f2b(v.y * scale * w[base + 1]);
  out[(size_t)t * DIM + base + 2] = f2b(v.z * scale * w[base + 2]);
  out[(size_t)t * DIM + base + 3] = f2b(v.w * scale * w[base + 3]);
}

extern "C" void kernel_launch(void* const* d_in, const int* in_sizes, int n_in,
                              void* d_out, int out_size, void* d_ws, size_t ws_size,
                              hipStream_t stream) {
  const int*   x    = (const int*)d_in[0];
  const float* emb  = (const float*)d_in[1];
  const float* Wp   = (const float*)d_in[2];
  const float* cw   = (const float*)d_in[3];
  const float* cb   = (const float*)d_in[4];
  const float* dtb  = (const float*)d_in[5];
  const float* alog = (const float*)d_in[6];
  const float* Dw   = (const float*)d_in[7];
  const float* gw   = (const float*)d_in[8];
  const float* Wo   = (const float*)d_in[9];
  const float* fnw  = (const float*)d_in[10];

  char* w = (char*)d_ws;
  auto alloc = [&](size_t bytes) {
    char* p = w; w += (bytes + 255) & ~(size_t)255; return p;
  };
  float* h_f32          = (float*)alloc((size_t)BT * DIM * 4);
  unsigned short* hb    = (unsigned short*)alloc((size_t)BT * DIM * 2);
  unsigned short* zx    = (unsigned short*)alloc((size_t)BT * DINPROJ * 2);
  float* dtraw          = (float*)alloc((size_t)BT * NHEADS * 4);
  float* dtf            = (float*)alloc((size_t)BT * NHEADS * 4);
  float* dAf            = (float*)alloc((size_t)BT * NHEADS * 4);
  unsigned short* xbc   = (unsigned short*)alloc((size_t)BT * CONVCH * 2);
  float* bcf            = (float*)alloc((size_t)BT * 256 * 4);
  unsigned short* yg    = (unsigned short*)alloc((size_t)BT * DINNER * 2);
  unsigned short* yn    = (unsigned short*)alloc((size_t)BT * DINNER * 2);
  unsigned short* hn    = (unsigned short*)alloc((size_t)BT * DIM * 2);
  unsigned short* Wp_b  = (unsigned short*)alloc((size_t)2 * DINPROJ * DIM * 2);
  unsigned short* Wo_b  = (unsigned short*)alloc((size_t)2 * DIM * DINNER * 2);
  unsigned short* emb_b = (unsigned short*)alloc((size_t)256 * DIM * 2);

  // fp32 -> bf16 weight conversions
  {
    int nWp = 2 * DINPROJ * DIM;
    int nWo = 2 * DIM * DINNER;
    int nEm = 256 * DIM;
    cvt_k<<<(nWp / 4 + 255) / 256, 256, 0, stream>>>(Wp, Wp_b, nWp);
    cvt_k<<<(nWo / 4 + 255) / 256, 256, 0, stream>>>(Wo, Wo_b, nWo);
    cvt_k<<<(nEm / 4 + 255) / 256, 256, 0, stream>>>(emb, emb_b, nEm);
  }

  embed_k<<<BT, 256, 0, stream>>>(x, emb, h_f32, hb);

  for (int l = 0; l < 2; ++l) {
    const unsigned short* Wpl = Wp_b + (size_t)l * DINPROJ * DIM;
    const unsigned short* Wol = Wo_b + (size_t)l * DIM * DINNER;
    const float* cwl   = cw + (size_t)l * CONVCH * 4;
    const float* cbl   = cb + (size_t)l * CONVCH;
    const float* dtbl  = dtb + l * NHEADS;
    const float* alogl = alog + l * NHEADS;
    const float* Dwl   = Dw + l * NHEADS;
    const float* gwl   = gw + (size_t)l * DINNER;

    gemm_bt<0><<<dim3(35, 16), 256, 0, stream>>>(hb, Wpl, BT, DINPROJ, DIM, zx, dtraw, nullptr);
    conv_k<<<BT, 256, 0, stream>>>(zx, cwl, cbl, xbc, bcf);
    dt_k<<<BT * NHEADS / 256, 256, 0, stream>>>(dtraw, dtbl, alogl, dtf, dAf);
    scan_k<<<512, 64, 0, stream>>>(xbc, bcf, zx, dtf, dAf, Dwl, yg);
    rms2048_k<<<BT, 256, 0, stream>>>(yg, gwl, yn);
    gemm_bt<1><<<dim3(8, 16), 256, 0, stream>>>(yn, Wol, BT, DIM, DINNER, nullptr, h_f32, hb);
  }

  rmsfinal_k<<<BT, 256, 0, stream>>>(h_f32, fnw, hn);
  gemm_bt<2><<<dim3(2, 16), 256, 0, stream>>>(hn, emb_b, BT, 256, DIM,
                                              nullptr, (float*)d_out, nullptr);
}

// Round 5
// 491.232 us; speedup vs baseline: 2.7270x; 2.1935x over previous
//
#include <hip/hip_runtime.h>
#include <hip/hip_bf16.h>

#define BT 2048
#define T_SEQ 1024
#define DIM 1024
#define DINNER 2048
#define DSTATE 128
#define HEADDIM 64
#define NHEADS 32
#define CONVCH 2304
#define DINPROJ 4384
#define EPS_F 1e-5f
#define NCHUNK 16   // T_SEQ / 64

typedef __bf16 bf16x8 __attribute__((ext_vector_type(8)));
typedef float f32x4 __attribute__((ext_vector_type(4)));

__device__ __forceinline__ float b2f(unsigned short u) {
  union { unsigned int i; float f; } v; v.i = ((unsigned int)u) << 16; return v.f;
}
__device__ __forceinline__ unsigned short f2b(float f) {
  unsigned int x = __float_as_uint(f);
  return (unsigned short)((x + 0x7fffu + ((x >> 16) & 1u)) >> 16);
}

// async global->LDS DMA (gemm staging)
__device__ __forceinline__ void gload_lds16(const void* g, void* l) {
  __builtin_amdgcn_global_load_lds(
      (const __attribute__((address_space(1))) unsigned int*)g,
      (__attribute__((address_space(3))) unsigned int*)l, 16, 0, 0);
}

// ---------------- fp32 -> bf16 weight conversion ----------------
__global__ void cvt_k(const float* __restrict__ in, unsigned short* __restrict__ out, int n) {
  int i = (blockIdx.x * 256 + threadIdx.x) * 4;
  if (i < n) {
    float4 v = *(const float4*)(in + i);
    out[i + 0] = f2b(v.x);
    out[i + 1] = f2b(v.y);
    out[i + 2] = f2b(v.z);
    out[i + 3] = f2b(v.w);
  }
}

// ---------------- embed lookup ----------------
__global__ void embed_k(const int* __restrict__ x, const float* __restrict__ emb,
                        float* __restrict__ h, unsigned short* __restrict__ hb) {
  int t = blockIdx.x;
  int tok = x[t];
  int d = threadIdx.x;
#pragma unroll
  for (int j = 0; j < 4; ++j, d += 256) {
    float v = emb[(size_t)tok * DIM + d];
    h[(size_t)t * DIM + d] = v;
    hb[(size_t)t * DIM + d] = f2b(v);
  }
}

// ---------------- GEMM: C[M,N] = A[M,K] * Bw[N,K]^T (bf16, fp32 acc) ----------------
template <int MODE>
__global__ void gemm_bt(const unsigned short* __restrict__ A,
                        const unsigned short* __restrict__ Bw,
                        int M, int N, int K,
                        unsigned short* __restrict__ Cout,
                        float* __restrict__ aux,
                        unsigned short* __restrict__ aux2) {
  __shared__ __align__(16) unsigned short As[128 * 32];
  __shared__ __align__(16) unsigned short Bs[128 * 32];
  const int tid = threadIdx.x;
  const int lane = tid & 63;
  const int wave = tid >> 6;
  const int m0 = blockIdx.y * 128;
  const int n0 = blockIdx.x * 128;
  const int wm = (wave >> 1) * 64;
  const int wn = (wave & 1) * 64;
  const int quad = lane >> 4;
  const int r = lane & 15;

  f32x4 acc[4][4];
#pragma unroll
  for (int i = 0; i < 4; ++i)
#pragma unroll
    for (int j = 0; j < 4; ++j) acc[i][j] = f32x4{0.f, 0.f, 0.f, 0.f};

  const int idx0 = tid, idx1 = tid + 256;
  const int ra0 = idx0 >> 2, ca0 = (idx0 & 3) * 8;
  const int ra1 = idx1 >> 2, ca1 = (idx1 & 3) * 8;
  int rb0 = n0 + ra0; if (rb0 >= N) rb0 = N - 1;
  int rb1 = n0 + ra1; if (rb1 >= N) rb1 = N - 1;

  unsigned short* asD0 = As + wave * 512;
  unsigned short* asD1 = As + 2048 + wave * 512;
  unsigned short* bsD0 = Bs + wave * 512;
  unsigned short* bsD1 = Bs + 2048 + wave * 512;
  const unsigned short* aG0 = A + (size_t)(m0 + ra0) * K + ca0;
  const unsigned short* aG1 = A + (size_t)(m0 + ra1) * K + ca1;
  const unsigned short* bG0 = Bw + (size_t)rb0 * K + ca0;
  const unsigned short* bG1 = Bw + (size_t)rb1 * K + ca1;

  for (int k0 = 0; k0 < K; k0 += 32) {
    __syncthreads();
    gload_lds16(aG0 + k0, asD0);
    gload_lds16(aG1 + k0, asD1);
    gload_lds16(bG0 + k0, bsD0);
    gload_lds16(bG1 + k0, bsD1);
    __syncthreads();
    const bf16x8* ap = (const bf16x8*)As;
    const bf16x8* bp = (const bf16x8*)Bs;
    bf16x8 af[4], bfr[4];
#pragma unroll
    for (int mt = 0; mt < 4; ++mt) af[mt] = ap[(wm + mt * 16 + r) * 4 + quad];
#pragma unroll
    for (int nt = 0; nt < 4; ++nt) bfr[nt] = bp[(wn + nt * 16 + r) * 4 + quad];
#pragma unroll
    for (int mt = 0; mt < 4; ++mt)
#pragma unroll
      for (int nt = 0; nt < 4; ++nt)
        acc[mt][nt] = __builtin_amdgcn_mfma_f32_16x16x32_bf16(af[mt], bfr[nt], acc[mt][nt], 0, 0, 0);
  }

#pragma unroll
  for (int mt = 0; mt < 4; ++mt) {
#pragma unroll
    for (int nt = 0; nt < 4; ++nt) {
#pragma unroll
      for (int i = 0; i < 4; ++i) {
        int gm = m0 + wm + mt * 16 + quad * 4 + i;
        int gn = n0 + wn + nt * 16 + r;
        if (gn < N) {
          float v = acc[mt][nt][i];
          if (MODE == 0) {
            Cout[(size_t)gm * N + gn] = f2b(v);
            if (gn >= DINNER + CONVCH)
              aux[(size_t)gm * NHEADS + (gn - (DINNER + CONVCH))] = v;
          } else if (MODE == 1) {
            size_t o = (size_t)gm * N + gn;
            float hnv = aux[o] + v;
            aux[o] = hnv;
            aux2[o] = f2b(hnv);
          } else {
            aux[(size_t)gm * N + gn] = v;
          }
        }
      }
    }
  }
}

// ---------------- causal conv (K=4) + silu ----------------
// outputs: xbc bf16 [t][2304]; bcb bf16 [t][256] (B|C rows for MFMA);
//          xsT bf16 [b][h][p][t] (x transposed, p-major -> MFMA B-operand)
__global__ void conv_k(const unsigned short* __restrict__ zx,
                       const float* __restrict__ cw,
                       const float* __restrict__ cb,
                       unsigned short* __restrict__ xbc,
                       unsigned short* __restrict__ bcb,
                       unsigned short* __restrict__ xsT) {
  int t = blockIdx.x;
  int tt = t & (T_SEQ - 1);
  int b = t >> 10;
  for (int c = threadIdx.x; c < CONVCH; c += 256) {
    float acc = cb[c];
#pragma unroll
    for (int k = 0; k < 4; ++k) {
      int tp = tt - 3 + k;
      if (tp >= 0)
        acc += b2f(zx[(size_t)(t - 3 + k) * DINPROJ + DINNER + c]) * cw[c * 4 + k];
    }
    float s = acc / (1.f + expf(-acc));
    unsigned short sb = f2b(s);
    xbc[(size_t)t * CONVCH + c] = sb;
    if (c >= DINNER) {
      bcb[(size_t)t * 256 + (c - DINNER)] = sb;
    } else {
      int hh = c >> 6, p = c & 63;
      xsT[(((size_t)b * NHEADS + hh) * HEADDIM + p) * T_SEQ + tt] = sb;
    }
  }
}

// ---------------- dt = softplus(dt_raw + bias); lnA = -dt*exp(A_log) ----------------
__global__ void dt_k(const float* __restrict__ dtraw, const float* __restrict__ dtb,
                     const float* __restrict__ alog,
                     float* __restrict__ dtf, float* __restrict__ lnAf) {
  int i = blockIdx.x * 256 + threadIdx.x;
  int h = i & (NHEADS - 1);
  float xx = dtraw[i] + dtb[h];
  float sp = (xx > 20.f) ? xx : log1pf(expf(xx));
  dtf[i] = sp;
  lnAf[i] = -sp * expf(alog[h]);
}

// ---------------- SSD pass 1: intra-chunk (per (b,h,chunk)) ----------------
// G = C·B^T; M[t][u] = G*w (w = exp(cum[t]-cum[u])*dt[u], u<=t); Y1 = M·X;
// Slocal = (X^T*ws)·B with ws[u] = dt[u]*exp(cum[63]-cum[u]).
__global__ __launch_bounds__(256) void ssd_intra(
    const unsigned short* __restrict__ bcb,
    const unsigned short* __restrict__ xsT,
    const float* __restrict__ dtf, const float* __restrict__ lnAf,
    unsigned short* __restrict__ y1buf, unsigned short* __restrict__ SL,
    float* __restrict__ dtot) {
  const int bi = blockIdx.x;           // ((b*32+h)*16 + c), 1024 blocks
  const int c = bi & 15;
  const int h = (bi >> 4) & 31;
  const int b = bi >> 9;
  const int tid = threadIdx.x;
  const int w = tid >> 6, l = tid & 63, r = l & 15, quad = l >> 4;
  const size_t tok0 = (size_t)b * T_SEQ + c * 64;

  __shared__ __align__(16) unsigned short BCs[64 * 264];  // [t][B0..127|C128..255]+pad
  __shared__ __align__(16) unsigned short XTs[64 * 72];   // [p][u]
  __shared__ __align__(16) unsigned short XWs[64 * 72];   // [p][u] * ws[u]
  __shared__ __align__(16) unsigned short Ms[64 * 72];    // [t][u]
  __shared__ float cumL[64], dtL[64];

#pragma unroll
  for (int i = 0; i < 8; ++i) {
    int idx = tid + i * 256;
    int row = idx >> 5, col = (idx & 31) * 8;
    uint4 v = *(const uint4*)(bcb + (tok0 + row) * 256 + col);
    *(uint4*)(BCs + row * 264 + col) = v;
  }
  const size_t xtb = ((size_t)(b * NHEADS + h) * HEADDIM) * T_SEQ + c * 64;
#pragma unroll
  for (int i = 0; i < 2; ++i) {
    int idx = tid + i * 256;
    int row = idx >> 3, col = (idx & 7) * 8;
    uint4 v = *(const uint4*)(xsT + xtb + (size_t)row * T_SEQ + col);
    *(uint4*)(XTs + row * 72 + col) = v;
  }
  if (tid < 64) {
    float v = lnAf[(tok0 + tid) * NHEADS + h];
    dtL[tid] = dtf[(tok0 + tid) * NHEADS + h];
#pragma unroll
    for (int off = 1; off < 64; off <<= 1) {
      float u = __shfl_up(v, off, 64);
      if (tid >= off) v += u;
    }
    cumL[tid] = v;
    if (tid == 63) dtot[bi] = expf(v);
  }
  __syncthreads();

  const float cum63 = cumL[63];
#pragma unroll
  for (int i = 0; i < 16; ++i) {
    int idx = tid + i * 256;
    int p = idx >> 6, u = idx & 63;
    float ws = dtL[u] * expf(cum63 - cumL[u]);
    XWs[p * 72 + u] = f2b(b2f(XTs[p * 72 + u]) * ws);
  }

  // GEMM1: G = C·B^T  (64x64, K=128)
  f32x4 g[4];
#pragma unroll
  for (int nt = 0; nt < 4; ++nt) g[nt] = f32x4{0.f, 0.f, 0.f, 0.f};
#pragma unroll
  for (int kk = 0; kk < 4; ++kk) {
    bf16x8 afr = *(const bf16x8*)(BCs + (w * 16 + r) * 264 + 128 + kk * 32 + quad * 8);
#pragma unroll
    for (int nt = 0; nt < 4; ++nt) {
      bf16x8 bfr = *(const bf16x8*)(BCs + (nt * 16 + r) * 264 + kk * 32 + quad * 8);
      g[nt] = __builtin_amdgcn_mfma_f32_16x16x32_bf16(afr, bfr, g[nt], 0, 0, 0);
    }
  }
#pragma unroll
  for (int nt = 0; nt < 4; ++nt) {
#pragma unroll
    for (int i = 0; i < 4; ++i) {
      int t_ = w * 16 + quad * 4 + i;
      int u_ = nt * 16 + r;
      float wv = (u_ <= t_) ? expf(cumL[t_] - cumL[u_]) * dtL[u_] : 0.f;
      Ms[t_ * 72 + u_] = f2b(g[nt][i] * wv);
    }
  }
  __syncthreads();

  // GEMM2: Y1 = M·X  (64t x 64p, K=64u)
  f32x4 y1[4];
#pragma unroll
  for (int nt = 0; nt < 4; ++nt) y1[nt] = f32x4{0.f, 0.f, 0.f, 0.f};
#pragma unroll
  for (int kk = 0; kk < 2; ++kk) {
    bf16x8 afr = *(const bf16x8*)(Ms + (w * 16 + r) * 72 + kk * 32 + quad * 8);
#pragma unroll
    for (int nt = 0; nt < 4; ++nt) {
      bf16x8 bfr = *(const bf16x8*)(XTs + (nt * 16 + r) * 72 + kk * 32 + quad * 8);
      y1[nt] = __builtin_amdgcn_mfma_f32_16x16x32_bf16(afr, bfr, y1[nt], 0, 0, 0);
    }
  }
#pragma unroll
  for (int nt = 0; nt < 4; ++nt)
#pragma unroll
    for (int i = 0; i < 4; ++i) {
      int t_ = w * 16 + quad * 4 + i, p_ = nt * 16 + r;
      y1buf[((size_t)bi * 64 + t_) * 64 + p_] = f2b(y1[nt][i]);
    }

  // GEMM3: Slocal = XW·B  (64p x 128n, K=64u); B-operand frag built transposed
  f32x4 sl[8];
#pragma unroll
  for (int nt = 0; nt < 8; ++nt) sl[nt] = f32x4{0.f, 0.f, 0.f, 0.f};
#pragma unroll
  for (int kk = 0; kk < 2; ++kk) {
    bf16x8 afr = *(const bf16x8*)(XWs + (w * 16 + r) * 72 + kk * 32 + quad * 8);
#pragma unroll
    for (int nt = 0; nt < 8; ++nt) {
      union { bf16x8 v; unsigned short u[8]; } bq;
#pragma unroll
      for (int j = 0; j < 8; ++j)
        bq.u[j] = BCs[(kk * 32 + quad * 8 + j) * 264 + nt * 16 + r];
      sl[nt] = __builtin_amdgcn_mfma_f32_16x16x32_bf16(afr, bq.v, sl[nt], 0, 0, 0);
    }
  }
#pragma unroll
  for (int nt = 0; nt < 8; ++nt)
#pragma unroll
    for (int i = 0; i < 4; ++i) {
      int p_ = w * 16 + quad * 4 + i, n_ = nt * 16 + r;
      SL[((size_t)bi * 64 + p_) * 128 + n_] = f2b(sl[nt][i]);
    }
}

// ---------------- SSD pass 2: chunk-state recurrence (in-place Slocal -> Spre) --------
__global__ void ssd_state(unsigned short* __restrict__ SL,
                          const float* __restrict__ dtot) {
  int gidx = blockIdx.x * 256 + threadIdx.x;   // 131072 = 64bh * 64p * 32(n/4)
  int n4 = (gidx & 31) * 4;
  int p = (gidx >> 5) & 63;
  int bh = gidx >> 11;
  float sx = 0.f, sy = 0.f, sz = 0.f, sw = 0.f;
  for (int c = 0; c < NCHUNK; ++c) {
    size_t off = ((size_t)(bh * 16 + c) * 64 + p) * 128 + n4;
    uint2 lv = *(uint2*)(SL + off);
    float d = dtot[bh * 16 + c];
    uint2 sv;
    sv.x = (unsigned)f2b(sx) | ((unsigned)f2b(sy) << 16);
    sv.y = (unsigned)f2b(sz) | ((unsigned)f2b(sw) << 16);
    *(uint2*)(SL + off) = sv;           // state BEFORE chunk c
    sx = d * sx + b2f(lv.x & 0xffff);
    sy = d * sy + b2f(lv.x >> 16);
    sz = d * sz + b2f(lv.y & 0xffff);
    sw = d * sw + b2f(lv.y >> 16);
  }
}

// ---------------- SSD pass 3: inter-chunk + combine + gate ----------------
__global__ __launch_bounds__(256) void ssd_inter(
    const unsigned short* __restrict__ bcb,
    const unsigned short* __restrict__ SL,       // holds Spre now
    const unsigned short* __restrict__ y1buf,
    const unsigned short* __restrict__ xbc,
    const unsigned short* __restrict__ zx,
    const float* __restrict__ lnAf,
    const float* __restrict__ Dw,
    unsigned short* __restrict__ yg) {
  const int bi = blockIdx.x;
  const int c = bi & 15, h = (bi >> 4) & 31, b = bi >> 9;
  const int tid = threadIdx.x;
  const int w = tid >> 6, l = tid & 63, r = l & 15, quad = l >> 4;
  const size_t tok0 = (size_t)b * T_SEQ + c * 64;

  __shared__ __align__(16) unsigned short Cs[64 * 136];
  __shared__ __align__(16) unsigned short Sp[64 * 136];
  __shared__ __align__(16) float Yf[64 * 68];
  __shared__ float cumL[64];

#pragma unroll
  for (int i = 0; i < 4; ++i) {
    int idx = tid + i * 256;
    int row = idx >> 4, col = (idx & 15) * 8;
    uint4 v = *(const uint4*)(bcb + (tok0 + row) * 256 + 128 + col);
    *(uint4*)(Cs + row * 136 + col) = v;
    uint4 s = *(const uint4*)(SL + ((size_t)bi * 64 + row) * 128 + col);
    *(uint4*)(Sp + row * 136 + col) = s;
  }
  if (tid < 64) {
    float v = lnAf[(tok0 + tid) * NHEADS + h];
#pragma unroll
    for (int off = 1; off < 64; off <<= 1) {
      float u = __shfl_up(v, off, 64);
      if (tid >= off) v += u;
    }
    cumL[tid] = v;
  }
  __syncthreads();

  // Yi[t][p] = sum_n C[t][n]*Spre[p][n]  (K=128)
  f32x4 yi[4];
#pragma unroll
  for (int nt = 0; nt < 4; ++nt) yi[nt] = f32x4{0.f, 0.f, 0.f, 0.f};
#pragma unroll
  for (int kk = 0; kk < 4; ++kk) {
    bf16x8 afr = *(const bf16x8*)(Cs + (w * 16 + r) * 136 + kk * 32 + quad * 8);
#pragma unroll
    for (int nt = 0; nt < 4; ++nt) {
      bf16x8 bfr = *(const bf16x8*)(Sp + (nt * 16 + r) * 136 + kk * 32 + quad * 8);
      yi[nt] = __builtin_amdgcn_mfma_f32_16x16x32_bf16(afr, bfr, yi[nt], 0, 0, 0);
    }
  }
#pragma unroll
  for (int nt = 0; nt < 4; ++nt)
#pragma unroll
    for (int i = 0; i < 4; ++i) {
      int t_ = w * 16 + quad * 4 + i, p_ = nt * 16 + r;
      float y1 = b2f(y1buf[((size_t)bi * 64 + t_) * 64 + p_]);
      Yf[t_ * 68 + p_] = y1 + expf(cumL[t_]) * yi[nt][i];
    }
  __syncthreads();

  // combine: y = Yf + D*x, gate with silu(z), write yg
  const float Dh = Dw[h];
  const int t_ = tid >> 2, pg = (tid & 3) * 16;
  const size_t tok = tok0 + t_;
  union { uint4 q[2]; unsigned short u[16]; } xv, zv, ov;
  xv.q[0] = *(const uint4*)(xbc + tok * CONVCH + h * 64 + pg);
  xv.q[1] = *(const uint4*)(xbc + tok * CONVCH + h * 64 + pg + 8);
  zv.q[0] = *(const uint4*)(zx + tok * DINPROJ + h * 64 + pg);
  zv.q[1] = *(const uint4*)(zx + tok * DINPROJ + h * 64 + pg + 8);
#pragma unroll
  for (int j = 0; j < 16; ++j) {
    float y = Yf[t_ * 68 + pg + j] + Dh * b2f(xv.u[j]);
    float zf = b2f(zv.u[j]);
    ov.u[j] = f2b(y * (zf / (1.f + expf(-zf))));
  }
  *(uint4*)(yg + tok * DINNER + h * 64 + pg) = ov.q[0];
  *(uint4*)(yg + tok * DINNER + h * 64 + pg + 8) = ov.q[1];
}

// ---------------- RMSNorm over 2048 ----------------
__global__ void rms2048_k(const unsigned short* __restrict__ in,
                          const float* __restrict__ w,
                          unsigned short* __restrict__ out) {
  int t = blockIdx.x;
  int base = threadIdx.x * 8;
  union { uint4 q; unsigned short u[8]; } vv;
  vv.q = *(const uint4*)(in + (size_t)t * DINNER + base);
  float f[8];
  float ss = 0.f;
#pragma unroll
  for (int j = 0; j < 8; ++j) { f[j] = b2f(vv.u[j]); ss += f[j] * f[j]; }
#pragma unroll
  for (int o = 32; o > 0; o >>= 1) ss += __shfl_xor(ss, o, 64);
  __shared__ float red[4];
  if ((threadIdx.x & 63) == 0) red[threadIdx.x >> 6] = ss;
  __syncthreads();
  ss = red[0] + red[1] + red[2] + red[3];
  float scale = rsqrtf(ss * (1.f / DINNER) + EPS_F);
#pragma unroll
  for (int j = 0; j < 8; ++j)
    out[(size_t)t * DINNER + base + j] = f2b(f[j] * scale * w[base + j]);
}

// ---------------- final RMSNorm over 1024 ----------------
__global__ void rmsfinal_k(const float* __restrict__ hf,
                           const float* __restrict__ w,
                           unsigned short* __restrict__ out) {
  int t = blockIdx.x;
  int base = threadIdx.x * 4;
  float4 v = *(const float4*)(hf + (size_t)t * DIM + base);
  float ss = v.x * v.x + v.y * v.y + v.z * v.z + v.w * v.w;
#pragma unroll
  for (int o = 32; o > 0; o >>= 1) ss += __shfl_xor(ss, o, 64);
  __shared__ float red[4];
  if ((threadIdx.x & 63) == 0) red[threadIdx.x >> 6] = ss;
  __syncthreads();
  ss = red[0] + red[1] + red[2] + red[3];
  float scale = rsqrtf(ss * (1.f / DIM) + EPS_F);
  out[(size_t)t * DIM + base + 0] = f2b(v.x * scale * w[base + 0]);
  out[(size_t)t * DIM + base + 1] = f2b(v.y * scale * w[base + 1]);
  out[(size_t)t * DIM + base + 2] = f2b(v.z * scale * w[base + 2]);
  out[(size_t)t * DIM + base + 3] = f2b(v.w * scale * w[base + 3]);
}

extern "C" void kernel_launch(void* const* d_in, const int* in_sizes, int n_in,
                              void* d_out, int out_size, void* d_ws, size_t ws_size,
                              hipStream_t stream) {
  const int*   x    = (const int*)d_in[0];
  const float* emb  = (const float*)d_in[1];
  const float* Wp   = (const float*)d_in[2];
  const float* cw   = (const float*)d_in[3];
  const float* cb   = (const float*)d_in[4];
  const float* dtb  = (const float*)d_in[5];
  const float* alog = (const float*)d_in[6];
  const float* Dw   = (const float*)d_in[7];
  const float* gw   = (const float*)d_in[8];
  const float* Wo   = (const float*)d_in[9];
  const float* fnw  = (const float*)d_in[10];

  char* w = (char*)d_ws;
  auto alloc = [&](size_t bytes) {
    char* p = w; w += (bytes + 255) & ~(size_t)255; return p;
  };
  float* h_f32          = (float*)alloc((size_t)BT * DIM * 4);
  unsigned short* hb    = (unsigned short*)alloc((size_t)BT * DIM * 2);
  unsigned short* zx    = (unsigned short*)alloc((size_t)BT * DINPROJ * 2);
  float* dtraw          = (float*)alloc((size_t)BT * NHEADS * 4);
  float* dtf            = (float*)alloc((size_t)BT * NHEADS * 4);
  float* lnAf           = (float*)alloc((size_t)BT * NHEADS * 4);
  unsigned short* xbc   = (unsigned short*)alloc((size_t)BT * CONVCH * 2);
  unsigned short* bcb   = (unsigned short*)alloc((size_t)BT * 256 * 2);
  unsigned short* xsT   = (unsigned short*)alloc((size_t)BT * DINNER * 2);
  unsigned short* SL    = (unsigned short*)alloc((size_t)1024 * 64 * 128 * 2);
  unsigned short* y1buf = (unsigned short*)alloc((size_t)1024 * 64 * 64 * 2);
  float* dtot           = (float*)alloc((size_t)1024 * 4);
  unsigned short* yg    = (unsigned short*)alloc((size_t)BT * DINNER * 2);
  unsigned short* yn    = (unsigned short*)alloc((size_t)BT * DINNER * 2);
  unsigned short* hn    = (unsigned short*)alloc((size_t)BT * DIM * 2);
  unsigned short* Wp_b  = (unsigned short*)alloc((size_t)2 * DINPROJ * DIM * 2);
  unsigned short* Wo_b  = (unsigned short*)alloc((size_t)2 * DIM * DINNER * 2);
  unsigned short* emb_b = (unsigned short*)alloc((size_t)256 * DIM * 2);

  {
    int nWp = 2 * DINPROJ * DIM;
    int nWo = 2 * DIM * DINNER;
    int nEm = 256 * DIM;
    cvt_k<<<(nWp / 4 + 255) / 256, 256, 0, stream>>>(Wp, Wp_b, nWp);
    cvt_k<<<(nWo / 4 + 255) / 256, 256, 0, stream>>>(Wo, Wo_b, nWo);
    cvt_k<<<(nEm / 4 + 255) / 256, 256, 0, stream>>>(emb, emb_b, nEm);
  }

  embed_k<<<BT, 256, 0, stream>>>(x, emb, h_f32, hb);

  for (int l = 0; l < 2; ++l) {
    const unsigned short* Wpl = Wp_b + (size_t)l * DINPROJ * DIM;
    const unsigned short* Wol = Wo_b + (size_t)l * DIM * DINNER;
    const float* cwl   = cw + (size_t)l * CONVCH * 4;
    const float* cbl   = cb + (size_t)l * CONVCH;
    const float* dtbl  = dtb + l * NHEADS;
    const float* alogl = alog + l * NHEADS;
    const float* Dwl   = Dw + l * NHEADS;
    const float* gwl   = gw + (size_t)l * DINNER;

    gemm_bt<0><<<dim3(35, 16), 256, 0, stream>>>(hb, Wpl, BT, DINPROJ, DIM, zx, dtraw, nullptr);
    conv_k<<<BT, 256, 0, stream>>>(zx, cwl, cbl, xbc, bcb, xsT);
    dt_k<<<BT * NHEADS / 256, 256, 0, stream>>>(dtraw, dtbl, alogl, dtf, lnAf);
    ssd_intra<<<1024, 256, 0, stream>>>(bcb, xsT, dtf, lnAf, y1buf, SL, dtot);
    ssd_state<<<512, 256, 0, stream>>>(SL, dtot);
    ssd_inter<<<1024, 256, 0, stream>>>(bcb, SL, y1buf, xbc, zx, lnAf, Dwl, yg);
    rms2048_k<<<BT, 256, 0, stream>>>(yg, gwl, yn);
    gemm_bt<1><<<dim3(8, 16), 256, 0, stream>>>(yn, Wol, BT, DIM, DINNER, nullptr, h_f32, hb);
  }

  rmsfinal_k<<<BT, 256, 0, stream>>>(h_f32, fnw, hn);
  gemm_bt<2><<<dim3(2, 16), 256, 0, stream>>>(hn, emb_b, BT, 256, DIM,
                                              nullptr, (float*)d_out, nullptr);
}

// Round 6
// 478.525 us; speedup vs baseline: 2.7995x; 1.0266x over previous
//
#include <hip/hip_runtime.h>
#include <hip/hip_bf16.h>

#define BT 2048
#define T_SEQ 1024
#define DIM 1024
#define DINNER 2048
#define DSTATE 128
#define HEADDIM 64
#define NHEADS 32
#define CONVCH 2304
#define DINPROJ 4384
#define EPS_F 1e-5f
#define NCHUNK 16   // T_SEQ / 64

typedef __bf16 bf16x8 __attribute__((ext_vector_type(8)));
typedef float f32x4 __attribute__((ext_vector_type(4)));

__device__ __forceinline__ float b2f(unsigned short u) {
  union { unsigned int i; float f; } v; v.i = ((unsigned int)u) << 16; return v.f;
}
__device__ __forceinline__ unsigned short f2b(float f) {
  unsigned int x = __float_as_uint(f);
  return (unsigned short)((x + 0x7fffu + ((x >> 16) & 1u)) >> 16);
}

// async global->LDS DMA (gemm staging)
__device__ __forceinline__ void gload_lds16(const void* g, void* l) {
  __builtin_amdgcn_global_load_lds(
      (const __attribute__((address_space(1))) unsigned int*)g,
      (__attribute__((address_space(3))) unsigned int*)l, 16, 0, 0);
}

// ---------------- fp32 -> bf16 weight conversion ----------------
__global__ void cvt_k(const float* __restrict__ in, unsigned short* __restrict__ out, int n) {
  int i = (blockIdx.x * 256 + threadIdx.x) * 4;
  if (i < n) {
    float4 v = *(const float4*)(in + i);
    out[i + 0] = f2b(v.x);
    out[i + 1] = f2b(v.y);
    out[i + 2] = f2b(v.z);
    out[i + 3] = f2b(v.w);
  }
}

// ---------------- embed lookup ----------------
__global__ void embed_k(const int* __restrict__ x, const float* __restrict__ emb,
                        float* __restrict__ h, unsigned short* __restrict__ hb) {
  int t = blockIdx.x;
  int tok = x[t];
  int d = threadIdx.x;
#pragma unroll
  for (int j = 0; j < 4; ++j, d += 256) {
    float v = emb[(size_t)tok * DIM + d];
    h[(size_t)t * DIM + d] = v;
    hb[(size_t)t * DIM + d] = f2b(v);
  }
}

// ---------------- GEMM: C[M,N] = A[M,K] * Bw[N,K]^T (bf16, fp32 acc) ----------------
// Templated tile TM x TN (64 or 128), 4 waves (2x2), global_load_lds staging.
// Smaller tiles -> more blocks/CU -> latency overlap (m102: blocks/CU drives the curve).
template <int MODE, int TM, int TN>
__global__ __launch_bounds__(256) void gemm_bt(
    const unsigned short* __restrict__ A,
    const unsigned short* __restrict__ Bw,
    int M, int N, int K,
    unsigned short* __restrict__ Cout,
    float* __restrict__ aux,
    unsigned short* __restrict__ aux2) {
  constexpr int FM = TM / 32, FN = TN / 32;
  constexpr int JA = TM / 64, JB = TN / 64;
  __shared__ __align__(16) unsigned short As[TM * 32];
  __shared__ __align__(16) unsigned short Bs[TN * 32];
  const int tid = threadIdx.x;
  const int lane = tid & 63;
  const int wave = tid >> 6;
  const int m0 = blockIdx.y * TM;
  const int n0 = blockIdx.x * TN;
  const int wm = (wave >> 1) * (TM / 2);
  const int wn = (wave & 1) * (TN / 2);
  const int quad = lane >> 4;
  const int r = lane & 15;

  f32x4 acc[FM][FN];
#pragma unroll
  for (int i = 0; i < FM; ++i)
#pragma unroll
    for (int j = 0; j < FN; ++j) acc[i][j] = f32x4{0.f, 0.f, 0.f, 0.f};

  const int rowt = tid >> 2, colt = (tid & 3) * 8;
  const unsigned short* aG[JA];
  unsigned short* aD[JA];
  const unsigned short* bG[JB];
  unsigned short* bD[JB];
#pragma unroll
  for (int j = 0; j < JA; ++j) {
    aG[j] = A + (size_t)(m0 + rowt + j * 64) * K + colt;
    aD[j] = As + wave * 512 + j * 2048;
  }
#pragma unroll
  for (int j = 0; j < JB; ++j) {
    int rb = n0 + rowt + j * 64; if (rb >= N) rb = N - 1;
    bG[j] = Bw + (size_t)rb * K + colt;
    bD[j] = Bs + wave * 512 + j * 2048;
  }

  for (int k0 = 0; k0 < K; k0 += 32) {
    __syncthreads();
#pragma unroll
    for (int j = 0; j < JA; ++j) gload_lds16(aG[j] + k0, aD[j]);
#pragma unroll
    for (int j = 0; j < JB; ++j) gload_lds16(bG[j] + k0, bD[j]);
    __syncthreads();  // drains vmcnt(0) -> staging visible
    const bf16x8* ap = (const bf16x8*)As;
    const bf16x8* bp = (const bf16x8*)Bs;
    bf16x8 af[FM], bfr[FN];
#pragma unroll
    for (int mt = 0; mt < FM; ++mt) af[mt] = ap[(wm + mt * 16 + r) * 4 + quad];
#pragma unroll
    for (int nt = 0; nt < FN; ++nt) bfr[nt] = bp[(wn + nt * 16 + r) * 4 + quad];
#pragma unroll
    for (int mt = 0; mt < FM; ++mt)
#pragma unroll
      for (int nt = 0; nt < FN; ++nt)
        acc[mt][nt] = __builtin_amdgcn_mfma_f32_16x16x32_bf16(af[mt], bfr[nt], acc[mt][nt], 0, 0, 0);
  }

#pragma unroll
  for (int mt = 0; mt < FM; ++mt) {
#pragma unroll
    for (int nt = 0; nt < FN; ++nt) {
#pragma unroll
      for (int i = 0; i < 4; ++i) {
        int gm = m0 + wm + mt * 16 + quad * 4 + i;
        int gn = n0 + wn + nt * 16 + r;
        if (gn < N) {
          float v = acc[mt][nt][i];
          if (MODE == 0) {
            Cout[(size_t)gm * N + gn] = f2b(v);
            if (gn >= DINNER + CONVCH)
              aux[(size_t)gm * NHEADS + (gn - (DINNER + CONVCH))] = v;
          } else if (MODE == 1) {
            size_t o = (size_t)gm * N + gn;
            float hnv = aux[o] + v;
            aux[o] = hnv;
            aux2[o] = f2b(hnv);
          } else {
            aux[(size_t)gm * N + gn] = v;
          }
        }
      }
    }
  }
}

// ---------------- causal conv (K=4) + silu ----------------
// outputs: xbc bf16 [t][2304]; bcb bf16 [t][256] (B|C rows for MFMA);
//          xsT bf16 [b][h][p][t] (x transposed, p-major -> MFMA B-operand)
__global__ void conv_k(const unsigned short* __restrict__ zx,
                       const float* __restrict__ cw,
                       const float* __restrict__ cb,
                       unsigned short* __restrict__ xbc,
                       unsigned short* __restrict__ bcb,
                       unsigned short* __restrict__ xsT) {
  int t = blockIdx.x;
  int tt = t & (T_SEQ - 1);
  int b = t >> 10;
  for (int c = threadIdx.x; c < CONVCH; c += 256) {
    float acc = cb[c];
#pragma unroll
    for (int k = 0; k < 4; ++k) {
      int tp = tt - 3 + k;
      if (tp >= 0)
        acc += b2f(zx[(size_t)(t - 3 + k) * DINPROJ + DINNER + c]) * cw[c * 4 + k];
    }
    float s = acc / (1.f + expf(-acc));
    unsigned short sb = f2b(s);
    xbc[(size_t)t * CONVCH + c] = sb;
    if (c >= DINNER) {
      bcb[(size_t)t * 256 + (c - DINNER)] = sb;
    } else {
      int hh = c >> 6, p = c & 63;
      xsT[(((size_t)b * NHEADS + hh) * HEADDIM + p) * T_SEQ + tt] = sb;
    }
  }
}

// ---------------- dt = softplus(dt_raw + bias); lnA = -dt*exp(A_log) ----------------
__global__ void dt_k(const float* __restrict__ dtraw, const float* __restrict__ dtb,
                     const float* __restrict__ alog,
                     float* __restrict__ dtf, float* __restrict__ lnAf) {
  int i = blockIdx.x * 256 + threadIdx.x;
  int h = i & (NHEADS - 1);
  float xx = dtraw[i] + dtb[h];
  float sp = (xx > 20.f) ? xx : log1pf(expf(xx));
  dtf[i] = sp;
  lnAf[i] = -sp * expf(alog[h]);
}

// ---------------- SSD pass 1: intra-chunk (per (b,h,chunk)) ----------------
__global__ __launch_bounds__(256) void ssd_intra(
    const unsigned short* __restrict__ bcb,
    const unsigned short* __restrict__ xsT,
    const float* __restrict__ dtf, const float* __restrict__ lnAf,
    unsigned short* __restrict__ y1buf, unsigned short* __restrict__ SL,
    float* __restrict__ dtot) {
  const int bi = blockIdx.x;           // ((b*32+h)*16 + c), 1024 blocks
  const int c = bi & 15;
  const int h = (bi >> 4) & 31;
  const int b = bi >> 9;
  const int tid = threadIdx.x;
  const int w = tid >> 6, l = tid & 63, r = l & 15, quad = l >> 4;
  const size_t tok0 = (size_t)b * T_SEQ + c * 64;

  __shared__ __align__(16) unsigned short BCs[64 * 264];  // [t][B0..127|C128..255]+pad
  __shared__ __align__(16) unsigned short XTs[64 * 72];   // [p][u]
  __shared__ __align__(16) unsigned short XWs[64 * 72];   // [p][u] * ws[u]
  __shared__ __align__(16) unsigned short Ms[64 * 72];    // [t][u]
  __shared__ float cumL[64], dtL[64];

#pragma unroll
  for (int i = 0; i < 8; ++i) {
    int idx = tid + i * 256;
    int row = idx >> 5, col = (idx & 31) * 8;
    uint4 v = *(const uint4*)(bcb + (tok0 + row) * 256 + col);
    *(uint4*)(BCs + row * 264 + col) = v;
  }
  const size_t xtb = ((size_t)(b * NHEADS + h) * HEADDIM) * T_SEQ + c * 64;
#pragma unroll
  for (int i = 0; i < 2; ++i) {
    int idx = tid + i * 256;
    int row = idx >> 3, col = (idx & 7) * 8;
    uint4 v = *(const uint4*)(xsT + xtb + (size_t)row * T_SEQ + col);
    *(uint4*)(XTs + row * 72 + col) = v;
  }
  if (tid < 64) {
    float v = lnAf[(tok0 + tid) * NHEADS + h];
    dtL[tid] = dtf[(tok0 + tid) * NHEADS + h];
#pragma unroll
    for (int off = 1; off < 64; off <<= 1) {
      float u = __shfl_up(v, off, 64);
      if (tid >= off) v += u;
    }
    cumL[tid] = v;
    if (tid == 63) dtot[bi] = expf(v);
  }
  __syncthreads();

  const float cum63 = cumL[63];
#pragma unroll
  for (int i = 0; i < 16; ++i) {
    int idx = tid + i * 256;
    int p = idx >> 6, u = idx & 63;
    float ws = dtL[u] * expf(cum63 - cumL[u]);
    XWs[p * 72 + u] = f2b(b2f(XTs[p * 72 + u]) * ws);
  }

  // GEMM1: G = C·B^T  (64x64, K=128)
  f32x4 g[4];
#pragma unroll
  for (int nt = 0; nt < 4; ++nt) g[nt] = f32x4{0.f, 0.f, 0.f, 0.f};
#pragma unroll
  for (int kk = 0; kk < 4; ++kk) {
    bf16x8 afr = *(const bf16x8*)(BCs + (w * 16 + r) * 264 + 128 + kk * 32 + quad * 8);
#pragma unroll
    for (int nt = 0; nt < 4; ++nt) {
      bf16x8 bfr = *(const bf16x8*)(BCs + (nt * 16 + r) * 264 + kk * 32 + quad * 8);
      g[nt] = __builtin_amdgcn_mfma_f32_16x16x32_bf16(afr, bfr, g[nt], 0, 0, 0);
    }
  }
#pragma unroll
  for (int nt = 0; nt < 4; ++nt) {
#pragma unroll
    for (int i = 0; i < 4; ++i) {
      int t_ = w * 16 + quad * 4 + i;
      int u_ = nt * 16 + r;
      float wv = (u_ <= t_) ? expf(cumL[t_] - cumL[u_]) * dtL[u_] : 0.f;
      Ms[t_ * 72 + u_] = f2b(g[nt][i] * wv);
    }
  }
  __syncthreads();

  // GEMM2: Y1 = M·X  (64t x 64p, K=64u)
  f32x4 y1[4];
#pragma unroll
  for (int nt = 0; nt < 4; ++nt) y1[nt] = f32x4{0.f, 0.f, 0.f, 0.f};
#pragma unroll
  for (int kk = 0; kk < 2; ++kk) {
    bf16x8 afr = *(const bf16x8*)(Ms + (w * 16 + r) * 72 + kk * 32 + quad * 8);
#pragma unroll
    for (int nt = 0; nt < 4; ++nt) {
      bf16x8 bfr = *(const bf16x8*)(XTs + (nt * 16 + r) * 72 + kk * 32 + quad * 8);
      y1[nt] = __builtin_amdgcn_mfma_f32_16x16x32_bf16(afr, bfr, y1[nt], 0, 0, 0);
    }
  }
#pragma unroll
  for (int nt = 0; nt < 4; ++nt)
#pragma unroll
    for (int i = 0; i < 4; ++i) {
      int t_ = w * 16 + quad * 4 + i, p_ = nt * 16 + r;
      y1buf[((size_t)bi * 64 + t_) * 64 + p_] = f2b(y1[nt][i]);
    }

  // GEMM3: Slocal = XW·B  (64p x 128n, K=64u); B-operand frag built transposed
  f32x4 sl[8];
#pragma unroll
  for (int nt = 0; nt < 8; ++nt) sl[nt] = f32x4{0.f, 0.f, 0.f, 0.f};
#pragma unroll
  for (int kk = 0; kk < 2; ++kk) {
    bf16x8 afr = *(const bf16x8*)(XWs + (w * 16 + r) * 72 + kk * 32 + quad * 8);
#pragma unroll
    for (int nt = 0; nt < 8; ++nt) {
      union { bf16x8 v; unsigned short u[8]; } bq;
#pragma unroll
      for (int j = 0; j < 8; ++j)
        bq.u[j] = BCs[(kk * 32 + quad * 8 + j) * 264 + nt * 16 + r];
      sl[nt] = __builtin_amdgcn_mfma_f32_16x16x32_bf16(afr, bq.v, sl[nt], 0, 0, 0);
    }
  }
#pragma unroll
  for (int nt = 0; nt < 8; ++nt)
#pragma unroll
    for (int i = 0; i < 4; ++i) {
      int p_ = w * 16 + quad * 4 + i, n_ = nt * 16 + r;
      SL[((size_t)bi * 64 + p_) * 128 + n_] = f2b(sl[nt][i]);
    }
}

// ---------------- SSD pass 2: chunk-state recurrence (in-place Slocal -> Spre) --------
__global__ void ssd_state(unsigned short* __restrict__ SL,
                          const float* __restrict__ dtot) {
  int gidx = blockIdx.x * 256 + threadIdx.x;   // 131072 = 64bh * 64p * 32(n/4)
  int n4 = (gidx & 31) * 4;
  int p = (gidx >> 5) & 63;
  int bh = gidx >> 11;
  float sx = 0.f, sy = 0.f, sz = 0.f, sw = 0.f;
  for (int c = 0; c < NCHUNK; ++c) {
    size_t off = ((size_t)(bh * 16 + c) * 64 + p) * 128 + n4;
    uint2 lv = *(uint2*)(SL + off);
    float d = dtot[bh * 16 + c];
    uint2 sv;
    sv.x = (unsigned)f2b(sx) | ((unsigned)f2b(sy) << 16);
    sv.y = (unsigned)f2b(sz) | ((unsigned)f2b(sw) << 16);
    *(uint2*)(SL + off) = sv;           // state BEFORE chunk c
    sx = d * sx + b2f(lv.x & 0xffff);
    sy = d * sy + b2f(lv.x >> 16);
    sz = d * sz + b2f(lv.y & 0xffff);
    sw = d * sw + b2f(lv.y >> 16);
  }
}

// ---------------- SSD pass 3: inter-chunk + combine + gate ----------------
__global__ __launch_bounds__(256) void ssd_inter(
    const unsigned short* __restrict__ bcb,
    const unsigned short* __restrict__ SL,       // holds Spre now
    const unsigned short* __restrict__ y1buf,
    const unsigned short* __restrict__ xbc,
    const unsigned short* __restrict__ zx,
    const float* __restrict__ lnAf,
    const float* __restrict__ Dw,
    unsigned short* __restrict__ yg) {
  const int bi = blockIdx.x;
  const int c = bi & 15, h = (bi >> 4) & 31, b = bi >> 9;
  const int tid = threadIdx.x;
  const int w = tid >> 6, l = tid & 63, r = l & 15, quad = l >> 4;
  const size_t tok0 = (size_t)b * T_SEQ + c * 64;

  __shared__ __align__(16) unsigned short Cs[64 * 136];
  __shared__ __align__(16) unsigned short Sp[64 * 136];
  __shared__ __align__(16) float Yf[64 * 68];
  __shared__ float cumL[64];

#pragma unroll
  for (int i = 0; i < 4; ++i) {
    int idx = tid + i * 256;
    int row = idx >> 4, col = (idx & 15) * 8;
    uint4 v = *(const uint4*)(bcb + (tok0 + row) * 256 + 128 + col);
    *(uint4*)(Cs + row * 136 + col) = v;
    uint4 s = *(const uint4*)(SL + ((size_t)bi * 64 + row) * 128 + col);
    *(uint4*)(Sp + row * 136 + col) = s;
  }
  if (tid < 64) {
    float v = lnAf[(tok0 + tid) * NHEADS + h];
#pragma unroll
    for (int off = 1; off < 64; off <<= 1) {
      float u = __shfl_up(v, off, 64);
      if (tid >= off) v += u;
    }
    cumL[tid] = v;
  }
  __syncthreads();

  // Yi[t][p] = sum_n C[t][n]*Spre[p][n]  (K=128)
  f32x4 yi[4];
#pragma unroll
  for (int nt = 0; nt < 4; ++nt) yi[nt] = f32x4{0.f, 0.f, 0.f, 0.f};
#pragma unroll
  for (int kk = 0; kk < 4; ++kk) {
    bf16x8 afr = *(const bf16x8*)(Cs + (w * 16 + r) * 136 + kk * 32 + quad * 8);
#pragma unroll
    for (int nt = 0; nt < 4; ++nt) {
      bf16x8 bfr = *(const bf16x8*)(Sp + (nt * 16 + r) * 136 + kk * 32 + quad * 8);
      yi[nt] = __builtin_amdgcn_mfma_f32_16x16x32_bf16(afr, bfr, yi[nt], 0, 0, 0);
    }
  }
#pragma unroll
  for (int nt = 0; nt < 4; ++nt)
#pragma unroll
    for (int i = 0; i < 4; ++i) {
      int t_ = w * 16 + quad * 4 + i, p_ = nt * 16 + r;
      float y1 = b2f(y1buf[((size_t)bi * 64 + t_) * 64 + p_]);
      Yf[t_ * 68 + p_] = y1 + expf(cumL[t_]) * yi[nt][i];
    }
  __syncthreads();

  // combine: y = Yf + D*x, gate with silu(z), write yg
  const float Dh = Dw[h];
  const int t_ = tid >> 2, pg = (tid & 3) * 16;
  const size_t tok = tok0 + t_;
  union { uint4 q[2]; unsigned short u[16]; } xv, zv, ov;
  xv.q[0] = *(const uint4*)(xbc + tok * CONVCH + h * 64 + pg);
  xv.q[1] = *(const uint4*)(xbc + tok * CONVCH + h * 64 + pg + 8);
  zv.q[0] = *(const uint4*)(zx + tok * DINPROJ + h * 64 + pg);
  zv.q[1] = *(const uint4*)(zx + tok * DINPROJ + h * 64 + pg + 8);
#pragma unroll
  for (int j = 0; j < 16; ++j) {
    float y = Yf[t_ * 68 + pg + j] + Dh * b2f(xv.u[j]);
    float zf = b2f(zv.u[j]);
    ov.u[j] = f2b(y * (zf / (1.f + expf(-zf))));
  }
  *(uint4*)(yg + tok * DINNER + h * 64 + pg) = ov.q[0];
  *(uint4*)(yg + tok * DINNER + h * 64 + pg + 8) = ov.q[1];
}

// ---------------- RMSNorm over 2048 ----------------
__global__ void rms2048_k(const unsigned short* __restrict__ in,
                          const float* __restrict__ w,
                          unsigned short* __restrict__ out) {
  int t = blockIdx.x;
  int base = threadIdx.x * 8;
  union { uint4 q; unsigned short u[8]; } vv;
  vv.q = *(const uint4*)(in + (size_t)t * DINNER + base);
  float f[8];
  float ss = 0.f;
#pragma unroll
  for (int j = 0; j < 8; ++j) { f[j] = b2f(vv.u[j]); ss += f[j] * f[j]; }
#pragma unroll
  for (int o = 32; o > 0; o >>= 1) ss += __shfl_xor(ss, o, 64);
  __shared__ float red[4];
  if ((threadIdx.x & 63) == 0) red[threadIdx.x >> 6] = ss;
  __syncthreads();
  ss = red[0] + red[1] + red[2] + red[3];
  float scale = rsqrtf(ss * (1.f / DINNER) + EPS_F);
#pragma unroll
  for (int j = 0; j < 8; ++j)
    out[(size_t)t * DINNER + base + j] = f2b(f[j] * scale * w[base + j]);
}

// ---------------- final RMSNorm over 1024 ----------------
__global__ void rmsfinal_k(const float* __restrict__ hf,
                           const float* __restrict__ w,
                           unsigned short* __restrict__ out) {
  int t = blockIdx.x;
  int base = threadIdx.x * 4;
  float4 v = *(const float4*)(hf + (size_t)t * DIM + base);
  float ss = v.x * v.x + v.y * v.y + v.z * v.z + v.w * v.w;
#pragma unroll
  for (int o = 32; o > 0; o >>= 1) ss += __shfl_xor(ss, o, 64);
  __shared__ float red[4];
  if ((threadIdx.x & 63) == 0) red[threadIdx.x >> 6] = ss;
  __syncthreads();
  ss = red[0] + red[1] + red[2] + red[3];
  float scale = rsqrtf(ss * (1.f / DIM) + EPS_F);
  out[(size_t)t * DIM + base + 0] = f2b(v.x * scale * w[base + 0]);
  out[(size_t)t * DIM + base + 1] = f2b(v.y * scale * w[base + 1]);
  out[(size_t)t * DIM + base + 2] = f2b(v.z * scale * w[base + 2]);
  out[(size_t)t * DIM + base + 3] = f2b(v.w * scale * w[base + 3]);
}

extern "C" void kernel_launch(void* const* d_in, const int* in_sizes, int n_in,
                              void* d_out, int out_size, void* d_ws, size_t ws_size,
                              hipStream_t stream) {
  const int*   x    = (const int*)d_in[0];
  const float* emb  = (const float*)d_in[1];
  const float* Wp   = (const float*)d_in[2];
  const float* cw   = (const float*)d_in[3];
  const float* cb   = (const float*)d_in[4];
  const float* dtb  = (const float*)d_in[5];
  const float* alog = (const float*)d_in[6];
  const float* Dw   = (const float*)d_in[7];
  const float* gw   = (const float*)d_in[8];
  const float* Wo   = (const float*)d_in[9];
  const float* fnw  = (const float*)d_in[10];

  char* w = (char*)d_ws;
  auto alloc = [&](size_t bytes) {
    char* p = w; w += (bytes + 255) & ~(size_t)255; return p;
  };
  float* h_f32          = (float*)alloc((size_t)BT * DIM * 4);
  unsigned short* hb    = (unsigned short*)alloc((size_t)BT * DIM * 2);
  unsigned short* zx    = (unsigned short*)alloc((size_t)BT * DINPROJ * 2);
  float* dtraw          = (float*)alloc((size_t)BT * NHEADS * 4);
  float* dtf            = (float*)alloc((size_t)BT * NHEADS * 4);
  float* lnAf           = (float*)alloc((size_t)BT * NHEADS * 4);
  unsigned short* xbc   = (unsigned short*)alloc((size_t)BT * CONVCH * 2);
  unsigned short* bcb   = (unsigned short*)alloc((size_t)BT * 256 * 2);
  unsigned short* xsT   = (unsigned short*)alloc((size_t)BT * DINNER * 2);
  unsigned short* SL    = (unsigned short*)alloc((size_t)1024 * 64 * 128 * 2);
  unsigned short* y1buf = (unsigned short*)alloc((size_t)1024 * 64 * 64 * 2);
  float* dtot           = (float*)alloc((size_t)1024 * 4);
  unsigned short* yg    = (unsigned short*)alloc((size_t)BT * DINNER * 2);
  unsigned short* yn    = (unsigned short*)alloc((size_t)BT * DINNER * 2);
  unsigned short* hn    = (unsigned short*)alloc((size_t)BT * DIM * 2);
  unsigned short* Wp_b  = (unsigned short*)alloc((size_t)2 * DINPROJ * DIM * 2);
  unsigned short* Wo_b  = (unsigned short*)alloc((size_t)2 * DIM * DINNER * 2);
  unsigned short* emb_b = (unsigned short*)alloc((size_t)256 * DIM * 2);

  {
    int nWp = 2 * DINPROJ * DIM;
    int nWo = 2 * DIM * DINNER;
    int nEm = 256 * DIM;
    cvt_k<<<(nWp / 4 + 255) / 256, 256, 0, stream>>>(Wp, Wp_b, nWp);
    cvt_k<<<(nWo / 4 + 255) / 256, 256, 0, stream>>>(Wo, Wo_b, nWo);
    cvt_k<<<(nEm / 4 + 255) / 256, 256, 0, stream>>>(emb, emb_b, nEm);
  }

  embed_k<<<BT, 256, 0, stream>>>(x, emb, h_f32, hb);

  for (int l = 0; l < 2; ++l) {
    const unsigned short* Wpl = Wp_b + (size_t)l * DINPROJ * DIM;
    const unsigned short* Wol = Wo_b + (size_t)l * DIM * DINNER;
    const float* cwl   = cw + (size_t)l * CONVCH * 4;
    const float* cbl   = cb + (size_t)l * CONVCH;
    const float* dtbl  = dtb + l * NHEADS;
    const float* alogl = alog + l * NHEADS;
    const float* Dwl   = Dw + l * NHEADS;
    const float* gwl   = gw + (size_t)l * DINNER;

    gemm_bt<0, 64, 64><<<dim3(69, 32), 256, 0, stream>>>(hb, Wpl, BT, DINPROJ, DIM, zx, dtraw, nullptr);
    conv_k<<<BT, 256, 0, stream>>>(zx, cwl, cbl, xbc, bcb, xsT);
    dt_k<<<BT * NHEADS / 256, 256, 0, stream>>>(dtraw, dtbl, alogl, dtf, lnAf);
    ssd_intra<<<1024, 256, 0, stream>>>(bcb, xsT, dtf, lnAf, y1buf, SL, dtot);
    ssd_state<<<512, 256, 0, stream>>>(SL, dtot);
    ssd_inter<<<1024, 256, 0, stream>>>(bcb, SL, y1buf, xbc, zx, lnAf, Dwl, yg);
    rms2048_k<<<BT, 256, 0, stream>>>(yg, gwl, yn);
    gemm_bt<1, 64, 64><<<dim3(16, 32), 256, 0, stream>>>(yn, Wol, BT, DIM, DINNER, nullptr, h_f32, hb);
  }

  rmsfinal_k<<<BT, 256, 0, stream>>>(h_f32, fnw, hn);
  gemm_bt<2, 64, 64><<<dim3(4, 32), 256, 0, stream>>>(hn, emb_b, BT, 256, DIM,
                                                      nullptr, (float*)d_out, nullptr);
}